// Round 10
// baseline (3765.925 us; speedup 1.0000x reference)
//
#include <hip/hip_runtime.h>

// B=1024, L=256, F=128, H=256, 3H=768, A=128, CH=256, OUT=512
#define B_ 1024
#define L_ 256
#define F_ 128
#define H_ 256

typedef __bf16 bf16x8 __attribute__((ext_vector_type(8)));
typedef __bf16 bf16x4 __attribute__((ext_vector_type(4)));
typedef float f32x4 __attribute__((ext_vector_type(4)));
typedef unsigned long long u64;

#define MFMA16(a, b, c) __builtin_amdgcn_mfma_f32_16x16x32_bf16((a), (b), (c), 0, 0, 0)

__device__ __forceinline__ float sigm(float x) { return 1.f / (1.f + __expf(-x)); }
__device__ __forceinline__ float tanh_f(float x) {
  float ax = fabsf(x);
  float e = __expf(-2.f * ax);
  float r = (1.f - e) / (1.f + e);
  return copysignf(r, x);
}
__device__ __forceinline__ bf16x8 ld8(const __bf16* p) { return *(const bf16x8*)p; }
__device__ __forceinline__ float wave_max(float v) {
#pragma unroll
  for (int d = 1; d < 64; d <<= 1) v = fmaxf(v, __shfl_xor(v, d));
  return v;
}
__device__ __forceinline__ float wave_sum(float v) {
#pragma unroll
  for (int d = 1; d < 64; d <<= 1) v += __shfl_xor(v, d);
  return v;
}

// ---- weight conversion: f32 -> bf16 (Wa also transposed to [A][H]) ----
__global__ void cvt_kernel(const float* __restrict__ wih_f, const float* __restrict__ whh_f,
                           const float* __restrict__ wout_f, const float* __restrict__ wa_f,
                           __bf16* __restrict__ wih, __bf16* __restrict__ whh,
                           __bf16* __restrict__ wout, __bf16* __restrict__ wa_t) {
  int i = blockIdx.x * 256 + threadIdx.x;
  if (i < 98304) wih[i] = (__bf16)wih_f[i];                           // [768][128]
  else if (i < 294912) whh[i - 98304] = (__bf16)whh_f[i - 98304];     // [768][256]
  else if (i < 327680) wout[i - 294912] = (__bf16)wout_f[i - 294912]; // [128][256]
  else if (i < 360448) {                                              // Wa[k][a] -> wa_t[a][k]
    int j = i - 327680;
    int a = j >> 8, k = j & 255;
    wa_t[j] = (__bf16)wa_f[k * 128 + a];
  }
}

// ---- gi precompute: gi[b,t,:] = x[b,t]@W_ih^T (+ folded biases), bf16.
// Layout for the 4-member/4-wave consumer: c16 = 2*w + hf (16-col gate group),
// m = c16>>2, wc = c16&3; chunk = (((t*64+G)*4+m)*4+wc)*3 + gate;
// within chunk: (lg*16+l15)*4 + r. Slabs t<=254 only (255 never consumed). ----
__global__ __launch_bounds__(512, 2) void gi_gemm_kernel(
    const float* __restrict__ x, const float* __restrict__ b_ih,
    const float* __restrict__ b_hh, const __bf16* __restrict__ wih,
    const int* __restrict__ tte, __bf16* __restrict__ gi) {
  const int tid = threadIdx.x;
  const int lane = tid & 63, w = tid >> 6;
  const int l15 = lane & 15, lg = lane >> 4, kofs = lg * 8;
  const int bblk = blockIdx.x & 63, tgrp = blockIdx.x >> 6;
  const int b0 = bblk * 16;

  int tmaxB = 0;
  for (int i = 0; i < 16; ++i) tmaxB = max(tmaxB, tte[b0 + i]);
  if (tgrp * 16 > tmaxB) return;

  bf16x8 wf[6][4];
  float bias[6];
#pragma unroll
  for (int tile = 0; tile < 6; ++tile) {
    const int gate = tile >> 1;
    const int c = w * 32 + (tile & 1) * 16 + l15;
    const int col = gate * 256 + c;
#pragma unroll
    for (int kt = 0; kt < 4; ++kt) wf[tile][kt] = ld8(wih + (size_t)col * 128 + kt * 32 + kofs);
    bias[tile] = (gate == 0) ? b_ih[c] + b_hh[c]
               : (gate == 1) ? b_ih[256 + c] + b_hh[256 + c]
                             : b_ih[512 + c];
  }

#pragma unroll 1
  for (int ti = 0; ti < 16; ++ti) {
    const int t = tgrp * 16 + ti;
    if (t > tmaxB || t > 254) break;
    const float* xb = x + ((size_t)(b0 + l15) * L_ + t) * F_ + kofs;
    bf16x8 xfr[4];
#pragma unroll
    for (int kt = 0; kt < 4; ++kt) {
      float4 a = *(const float4*)(xb + kt * 32);
      float4 b = *(const float4*)(xb + kt * 32 + 4);
      xfr[kt][0] = (__bf16)a.x; xfr[kt][1] = (__bf16)a.y;
      xfr[kt][2] = (__bf16)a.z; xfr[kt][3] = (__bf16)a.w;
      xfr[kt][4] = (__bf16)b.x; xfr[kt][5] = (__bf16)b.y;
      xfr[kt][6] = (__bf16)b.z; xfr[kt][7] = (__bf16)b.w;
    }
    f32x4 acc[6];
#pragma unroll
    for (int tile = 0; tile < 6; ++tile) {
      acc[tile][0] = bias[tile]; acc[tile][1] = bias[tile];
      acc[tile][2] = bias[tile]; acc[tile][3] = bias[tile];
    }
#pragma unroll
    for (int kt = 0; kt < 4; ++kt)
#pragma unroll
      for (int tile = 0; tile < 6; ++tile)
        acc[tile] = MFMA16(xfr[kt], wf[tile][kt], acc[tile]);

#pragma unroll
    for (int tile = 0; tile < 6; ++tile) {
      const int gate = tile >> 1;
      const int c16 = 2 * w + (tile & 1);
      const size_t chunk = (((size_t)t * 64 + bblk) * 4 + (c16 >> 2)) * 4 * 3
                         + (size_t)(c16 & 3) * 3 + gate;
      bf16x4 pk;
      pk[0] = (__bf16)acc[tile][0]; pk[1] = (__bf16)acc[tile][1];
      pk[2] = (__bf16)acc[tile][2]; pk[3] = (__bf16)acc[tile][3];
      *(bf16x4*)(gi + chunk * 256 + (lg * 16 + l15) * 4) = pk;
    }
  }
}

// ---- recurrence gru6: 256 blocks = 64 groups x 4 members; member owns 64
// h-cols; its 96 KB W_hh slice lives ENTIRELY in LDS (XOR-swizzled).
// Per step: LDS MFMA -> gates -> own slice to hbuf -> u64 atomic export to hx
// (L3) -> SINGLE-LANE store-then-spin flag handshake (deadlock-safe: store
// precedes spin in one divergent path) -> import partner slices -> next step. ----
__global__ __launch_bounds__(256) void gru6_kernel(
    const int* __restrict__ tte, const float* __restrict__ b_hh,
    const __bf16* __restrict__ whh, const __bf16* __restrict__ gi,
    __bf16* __restrict__ hid, __bf16* __restrict__ hx, int* __restrict__ flags) {
  __shared__ __bf16 wlds[3 * 64 * 256];   // 96 KB
  __shared__ __bf16 hbuf[2][16][264];     // 16.9 KB
  const int tid = threadIdx.x;
  const int lane = tid & 63, w = tid >> 6;          // 4 waves
  const int l15 = lane & 15, lg = lane >> 4, kofs = lg * 8;
  const int G = blockIdx.x & 63, m = blockIdx.x >> 6;
  const int b0 = G * 16;

  // stage W slice into LDS: row = g*64+c (c = local col), swizzle byte^=(c&7)<<4
  for (int idx = tid; idx < 192 * 32; idx += 256) {
    const int row = idx >> 5, k16 = idx & 31;
    const int g = row >> 6, c = row & 63;
    uint4 v = *(const uint4*)(whh + (size_t)(g * 256 + m * 64 + c) * 256 + k16 * 8);
    const int elem = ((row * 512 + ((k16 * 16) ^ ((c & 7) << 4))) >> 1);
    *(uint4*)&wlds[elem] = v;
  }
  for (int i = tid; i < 2 * 16 * 264; i += 256) ((__bf16*)hbuf)[i] = (__bf16)0.f;

  const int myc = w * 16 + l15;            // local col in [0,64)
  const int swz = (l15 & 7) << 4;
  const int wrow0 = (0 * 64 + myc) * 512, wrow1 = (1 * 64 + myc) * 512, wrow2 = (2 * 64 + myc) * 512;

  const float bhn = b_hh[512 + m * 64 + myc];
  int tteC[4];
#pragma unroll
  for (int r = 0; r < 4; ++r) tteC[r] = tte[b0 + 4 * lg + r];
  const int rowS = tid >> 4, csegS = tid & 15;
  const int tteS = tte[b0 + rowS];
  int tmax = 0;
  for (int i = 0; i < 16; ++i) tmax = max(tmax, tte[b0 + i]);

  int pmL[3];
#pragma unroll
  for (int j = 0; j < 3; ++j) pmL[j] = j + (j >= m ? 1 : 0);

  // gi base; per-t stride = 64*4*4*3*256 = 786432 bf16
  const __bf16* gib = gi + ((((size_t)G * 4 + m) * 4 + w) * 3) * 256 + (lg * 16 + l15) * 4;
  bf16x4 g0 = *(const bf16x4*)(gib);
  bf16x4 g1 = *(const bf16x4*)(gib + 256);
  bf16x4 g2 = *(const bf16x4*)(gib + 512);

  float hprev[4];
#pragma unroll
  for (int r = 0; r < 4; ++r) hprev[r] = 0.f;

  __syncthreads();

#pragma unroll 1
  for (int t = 0; t < tmax; ++t) {
    const int c = t & 1, nc = c ^ 1;
    f32x4 aR, aZ, aN;
#pragma unroll
    for (int r = 0; r < 4; ++r) { aR[r] = (float)g0[r]; aZ[r] = (float)g1[r]; aN[r] = bhn; }
    const bf16x4 gN = g2;

    // prefetch next step's gi (slab clamp 254: slab 255 never consumed)
    const __bf16* gp = gib + (size_t)min(t + 1, 254) * 786432;
    g0 = *(const bf16x4*)(gp);
    g1 = *(const bf16x4*)(gp + 256);
    g2 = *(const bf16x4*)(gp + 512);

    // gh over K=256: A from hbuf, B from LDS weights (swizzled)
#pragma unroll
    for (int kt = 0; kt < 8; ++kt) {
      const bf16x8 hA = *(const bf16x8*)&hbuf[c][l15][kt * 32 + kofs];
      const int kb = kt * 64 + lg * 16;
      aR = MFMA16(hA, *(const bf16x8*)&wlds[(wrow0 + (kb ^ swz)) >> 1], aR);
      aZ = MFMA16(hA, *(const bf16x8*)&wlds[(wrow1 + (kb ^ swz)) >> 1], aZ);
      aN = MFMA16(hA, *(const bf16x8*)&wlds[(wrow2 + (kb ^ swz)) >> 1], aN);
    }

    // gates + own-slice write (C-layout: row = 4*lg+r, col = m*64+myc)
#pragma unroll
    for (int r = 0; r < 4; ++r) {
      const float rg = sigm(aR[r]);
      const float zg = sigm(aZ[r]);
      const float ng = tanh_f((float)gN[r] + rg * aN[r]);
      const float hold = hprev[r];
      const float hnew = zg * (hold - ng) + ng;
      const float hw = (t < tteC[r]) ? hnew : hold;
      hprev[r] = hw;
      hbuf[nc][4 * lg + r][m * 64 + myc] = (__bf16)hw;
    }
    __syncthreads();   // #1: own slice complete in hbuf[nc]

    // export own slice (u64 per thread) + hid store
    const u64 own = *(const u64*)&hbuf[nc][rowS][m * 64 + csegS * 4];
    __hip_atomic_store(
        (u64*)(hx + (((size_t)nc * 64 + G) * 4 + m) * 1024 + rowS * 64 + csegS * 4),
        own, __ATOMIC_RELAXED, __HIP_MEMORY_SCOPE_AGENT);
    if (t < tteS)
      *(u64*)(hid + ((size_t)(b0 + rowS) * L_ + t) * H_ + m * 64 + csegS * 4) = own;
    __syncthreads();   // #2: drains all exports (vmcnt 0) before flag

    // SINGLE-LANE handshake: store own flag FIRST, then spin on partners.
    // One divergent path -> no intra-wave spin deadlock.
    if (tid == 0) {
      __hip_atomic_store(&flags[G * 4 + m], t + 1, __ATOMIC_RELEASE, __HIP_MEMORY_SCOPE_AGENT);
#pragma unroll 1
      for (int j = 0; j < 3; ++j) {
        const int pf = G * 4 + pmL[j];
        int guard = 0;
        while (__hip_atomic_load(&flags[pf], __ATOMIC_ACQUIRE, __HIP_MEMORY_SCOPE_AGENT) < t + 1) {
          if (++guard > 200000) break;   // bail -> wrong result, never a hang
        }
      }
    }
    __syncthreads();   // #3: partners ready (block-wide via barrier after acquire)

    // import 3 partner slices into hbuf[nc]
#pragma unroll
    for (int j = 0; j < 3; ++j) {
      const int pm = pmL[j];
      const u64 v = __hip_atomic_load(
          (const u64*)(hx + (((size_t)nc * 64 + G) * 4 + pm) * 1024 + rowS * 64 + csegS * 4),
          __ATOMIC_RELAXED, __HIP_MEMORY_SCOPE_AGENT);
      *(u64*)&hbuf[nc][rowS][pm * 64 + csegS * 4] = v;
    }
    __syncthreads();   // #4: hbuf[nc] full for next step
  }
}

// ---- out = mask ? hid@W_out^T + b_out : 0  (writes zeros; no d_out memset) ----
__global__ __launch_bounds__(512, 2) void out_gemm_kernel(
    const __bf16* __restrict__ hid, const __bf16* __restrict__ wout,
    const float* __restrict__ b_out, const int* __restrict__ tte,
    float* __restrict__ out) {
  const int tid = threadIdx.x;
  const int lane = tid & 63, w = tid >> 6;
  const int l15 = lane & 15, lg = lane >> 4, kofs = lg * 8;
  const int row0 = blockIdx.x * 128 + w * 16;
  const int bI = row0 >> 8;
  const int tteB = tte[bI];
  const int tbase = row0 & 255;

  f32x4 acc[8];
#pragma unroll
  for (int tile = 0; tile < 8; ++tile) { acc[tile][0] = 0; acc[tile][1] = 0; acc[tile][2] = 0; acc[tile][3] = 0; }
#pragma unroll
  for (int kt = 0; kt < 8; ++kt) {
    const bf16x8 af = *(const bf16x8*)(hid + (size_t)(row0 + l15) * H_ + kt * 32 + kofs);
#pragma unroll
    for (int tile = 0; tile < 8; ++tile)
      acc[tile] = MFMA16(af, ld8(wout + (size_t)(tile * 16 + l15) * H_ + kt * 32 + kofs), acc[tile]);
  }
#pragma unroll
  for (int tile = 0; tile < 8; ++tile) {
    const float bo = b_out[tile * 16 + l15];
#pragma unroll
    for (int r = 0; r < 4; ++r) {
      const int R = row0 + 4 * lg + r;
      const int t = tbase + 4 * lg + r;
      out[(size_t)R * F_ + tile * 16 + l15] = (t < tteB) ? acc[tile][r] + bo : 0.f;
    }
  }
}

// ---- decoder: attention (MFMA scores), softmax, context, MLP, final softmax ----
__global__ __launch_bounds__(256, 2) void decoder_kernel(
    const float* __restrict__ x, const int* __restrict__ tte,
    const __bf16* __restrict__ hid, const __bf16* __restrict__ wa_t,
    const float* __restrict__ va, const float* __restrict__ Ua,
    const float* __restrict__ W1, const float* __restrict__ b1,
    const float* __restrict__ W2, const float* __restrict__ b2,
    float* __restrict__ fht) {
  __shared__ float last_s[128], u_s[128], s_s[256], alpha_s[256], ctx_s[256], z1_s[256], red_s[8];
  const int tid = threadIdx.x;
  const int b = blockIdx.x;
  const int tb = tte[b];
  if (tid < 128) last_s[tid] = x[((size_t)b * L_ + tb) * F_ + tid];
  __syncthreads();
  if (tid < 128) {
    float a = 0.f;
    for (int f = 0; f < 128; ++f) a += last_s[f] * Ua[f * 128 + tid];
    u_s[tid] = a;
  }
  __syncthreads();
  const int lane = tid & 63, w = tid >> 6, l15 = lane & 15, lg = lane >> 4, kofs = lg * 8;
#pragma unroll 1
  for (int mi = 0; mi < 4; ++mi) {
    const int mtile = w * 4 + mi;
    const int trow = mtile * 16 + l15;
    f32x4 sacc[8];
#pragma unroll
    for (int ct = 0; ct < 8; ++ct) { sacc[ct][0] = 0; sacc[ct][1] = 0; sacc[ct][2] = 0; sacc[ct][3] = 0; }
#pragma unroll
    for (int kt = 0; kt < 8; ++kt) {
      bf16x8 af = *(const bf16x8*)&hid[((size_t)b * L_ + trow) * H_ + kt * 32 + kofs];
#pragma unroll
      for (int ct = 0; ct < 8; ++ct) {
        bf16x8 bf = *(const bf16x8*)&wa_t[(size_t)(ct * 16 + l15) * 256 + kt * 32 + kofs];
        sacc[ct] = MFMA16(af, bf, sacc[ct]);
      }
    }
    float sp[4] = {0, 0, 0, 0};
#pragma unroll
    for (int ct = 0; ct < 8; ++ct) {
      int a = ct * 16 + l15;
      float ua = u_s[a], vv = va[a];
#pragma unroll
      for (int r = 0; r < 4; ++r) sp[r] += tanh_f(sacc[ct][r] + ua) * vv;
    }
#pragma unroll
    for (int r = 0; r < 4; ++r) {
      sp[r] += __shfl_xor(sp[r], 1);
      sp[r] += __shfl_xor(sp[r], 2);
      sp[r] += __shfl_xor(sp[r], 4);
      sp[r] += __shfl_xor(sp[r], 8);
    }
    if (l15 == 0) {
#pragma unroll
      for (int r = 0; r < 4; ++r) s_s[mtile * 16 + 4 * lg + r] = sp[r];
    }
  }
  __syncthreads();
  const float sv = s_s[tid];
  float wm = wave_max(sv);
  if (lane == 0) red_s[w] = wm;
  __syncthreads();
  const float m = fmaxf(fmaxf(red_s[0], red_s[1]), fmaxf(red_s[2], red_s[3]));
  const float e = __expf(sv - m);
  alpha_s[tid] = e;
  float wsum = wave_sum(e);
  if (lane == 0) red_s[4 + w] = wsum;
  __syncthreads();
  const float inv = 1.f / (red_s[4] + red_s[5] + red_s[6] + red_s[7]);
  float cacc = 0.f;
  for (int t = 0; t < 256; ++t)
    cacc += alpha_s[t] * (float)hid[((size_t)b * L_ + t) * H_ + tid];
  ctx_s[tid] = cacc * inv;
  __syncthreads();
  float a1 = b1[tid];
  for (int k = 0; k < 256; ++k) a1 += ctx_s[k] * W1[k * 256 + tid];
  for (int k = 0; k < 128; ++k) a1 += last_s[k] * W1[(256 + k) * 256 + tid];
  z1_s[tid] = fmaxf(a1, 0.f);
  __syncthreads();
  float o0 = b2[tid], o1 = b2[tid + 256];
  for (int k = 0; k < 256; ++k) {
    float zv = z1_s[k];
    o0 += zv * W2[k * 512 + tid];
    o1 += zv * W2[k * 512 + tid + 256];
  }
  float wm2 = wave_max(fmaxf(o0, o1));
  if (lane == 0) red_s[w] = wm2;
  __syncthreads();
  const float m2 = fmaxf(fmaxf(red_s[0], red_s[1]), fmaxf(red_s[2], red_s[3]));
  const float e0 = __expf(o0 - m2), e1 = __expf(o1 - m2);
  float ws2 = wave_sum(e0 + e1);
  if (lane == 0) red_s[4 + w] = ws2;
  __syncthreads();
  const float inv2 = 1.f / (red_s[4] + red_s[5] + red_s[6] + red_s[7]);
  fht[(size_t)b * 512 + tid] = e0 * inv2;
  fht[(size_t)b * 512 + tid + 256] = e1 * inv2;
}

extern "C" void kernel_launch(void* const* d_in, const int* in_sizes, int n_in,
                              void* d_out, int out_size, void* d_ws, size_t ws_size,
                              hipStream_t stream) {
  const float* x = (const float*)d_in[0];
  const int* tte = (const int*)d_in[1];
  const float* W_ih = (const float*)d_in[2];
  const float* W_hh = (const float*)d_in[3];
  const float* b_ih = (const float*)d_in[4];
  const float* b_hh = (const float*)d_in[5];
  const float* W_out = (const float*)d_in[6];
  const float* b_out = (const float*)d_in[7];
  const float* Wa = (const float*)d_in[8];
  const float* Ua = (const float*)d_in[9];
  const float* va = (const float*)d_in[10];
  const float* W1 = (const float*)d_in[11];
  const float* b1 = (const float*)d_in[12];
  const float* W2 = (const float*)d_in[13];
  const float* b2 = (const float*)d_in[14];

  char* ws = (char*)d_ws;
  __bf16* wih = (__bf16*)(ws + 0);            // 196608 B
  __bf16* whh = (__bf16*)(ws + 196608);       // 393216 B
  __bf16* wout = (__bf16*)(ws + 589824);      // 65536 B
  __bf16* wa_t = (__bf16*)(ws + 655360);      // 65536 B
  __bf16* hid = (__bf16*)(ws + 1048576);      // 134217728 B
  __bf16* gi = (__bf16*)(ws + 135266304);     // 255 slabs x 1572864 B = 401080320
  __bf16* hx = (__bf16*)(ws + 536346624);     // 2*64*4*16*64*2 = 1048576 B
  int* flags = (int*)(ws + 537395200);        // 64*4*4 = 1024 B

  float* out = (float*)d_out;
  float* fht = out + (size_t)33554432;

  hipMemsetAsync(hid, 0, (size_t)134217728, stream);   // zero hidden past tte
  hipMemsetAsync(flags, 0, 1024, stream);              // exchange flags (per launch)
  cvt_kernel<<<1408, 256, 0, stream>>>(W_ih, W_hh, W_out, Wa, wih, whh, wout, wa_t);
  gi_gemm_kernel<<<1024, 512, 0, stream>>>(x, b_ih, b_hh, wih, tte, gi);
  gru6_kernel<<<256, 256, 0, stream>>>(tte, b_hh, whh, gi, hid, hx, flags);
  out_gemm_kernel<<<2048, 512, 0, stream>>>(hid, wout, b_out, tte, out);
  decoder_kernel<<<1024, 256, 0, stream>>>(x, tte, hid, wa_t, va, Ua, W1, b1, W2, b2, fht);
}

// Round 11
// 1316.323 us; speedup vs baseline: 2.8609x; 2.8609x over previous
//
#include <hip/hip_runtime.h>

// B=1024, L=256, F=128, H=256, 3H=768, A=128, CH=256, OUT=512
#define B_ 1024
#define L_ 256
#define F_ 128
#define H_ 256

typedef __bf16 bf16x8 __attribute__((ext_vector_type(8)));
typedef __bf16 bf16x4 __attribute__((ext_vector_type(4)));
typedef float f32x4 __attribute__((ext_vector_type(4)));
typedef int i32x4 __attribute__((ext_vector_type(4)));

#define MFMA16(a, b, c) __builtin_amdgcn_mfma_f32_16x16x32_bf16((a), (b), (c), 0, 0, 0)
#define MFMA_I8(a, b, c) __builtin_amdgcn_mfma_i32_16x16x64_i8((a), (b), (c), 0, 0, 0)

__device__ __forceinline__ float sigm(float x) { return 1.f / (1.f + __expf(-x)); }
__device__ __forceinline__ float tanh_f(float x) {
  float ax = fabsf(x);
  float e = __expf(-2.f * ax);
  float r = (1.f - e) / (1.f + e);
  return copysignf(r, x);
}
__device__ __forceinline__ bf16x8 ld8(const __bf16* p) { return *(const bf16x8*)p; }
__device__ __forceinline__ float wave_max(float v) {
#pragma unroll
  for (int d = 1; d < 64; d <<= 1) v = fmaxf(v, __shfl_xor(v, d));
  return v;
}
__device__ __forceinline__ float wave_sum(float v) {
#pragma unroll
  for (int d = 1; d < 64; d <<= 1) v += __shfl_xor(v, d);
  return v;
}

// ---- weight conversion: f32 -> bf16 (Wa transposed to [A][H]); W_hh handled by quant ----
__global__ void cvt_kernel(const float* __restrict__ wih_f, const float* __restrict__ wout_f,
                           const float* __restrict__ wa_f,
                           __bf16* __restrict__ wih, __bf16* __restrict__ wout,
                           __bf16* __restrict__ wa_t) {
  int i = blockIdx.x * 256 + threadIdx.x;
  if (i < 98304) wih[i] = (__bf16)wih_f[i];                            // [768][128]
  else if (i < 131072) wout[i - 98304] = (__bf16)wout_f[i - 98304];    // [128][256]
  else if (i < 163840) {                                               // Wa[k][a] -> wa_t[a][k]
    int j = i - 131072;
    int a = j >> 8, k = j & 255;
    wa_t[j] = (__bf16)wa_f[k * 128 + a];
  }
}

// ---- quantize W_hh to i8 with per-row (per-output-col) scales.
// rows 0..511 (r,z) -> wq_rz[512][256] row-major; rows 512..767 (n) ->
// wqn_f fragment layout: pos=(((w*2+hf)*4+kt)*64+lane)*16+j for
// w=cN>>5, hf=(cN>>4)&1, l15=cN&15, kt=k>>6, lg=(k>>4)&3, j=k&15, lane=lg*16+l15.
// dq[c] = max_c / (127*127). ----
__global__ void quant_kernel(const float* __restrict__ whh_f,
                             signed char* __restrict__ wq_rz,
                             signed char* __restrict__ wqn_f,
                             float* __restrict__ dq) {
  const int c = blockIdx.x * 256 + threadIdx.x;
  if (c >= 768) return;
  const float* row = whh_f + (size_t)c * 256;
  float m = 0.f;
  for (int k = 0; k < 256; ++k) m = fmaxf(m, fabsf(row[k]));
  const float inv = (m > 1e-30f) ? 127.f / m : 0.f;
  dq[c] = m / 16129.f;
  if (c < 512) {
    for (int k = 0; k < 256; ++k)
      wq_rz[(size_t)c * 256 + k] = (signed char)__float2int_rn(row[k] * inv);
  } else {
    const int cN = c - 512;
    const int w = cN >> 5, hf = (cN >> 4) & 1, l15 = cN & 15;
    for (int k = 0; k < 256; ++k) {
      const int kt = k >> 6, lg = (k >> 4) & 3, j = k & 15;
      const int lane = lg * 16 + l15;
      wqn_f[((((w * 2 + hf) * 4) + kt) * 64 + lane) * 16 + j] =
          (signed char)__float2int_rn(row[k] * inv);
    }
  }
}

// ---- gi precompute (8-wave layout): gi[b,t,:] = x[b,t]@W_ih^T (+ folded biases),
// chunk = ((t*64+bblk)*8+w)*6+tile, tile = gate*2+hf; within: (lg*16+l15)*4+r ----
__global__ __launch_bounds__(512, 2) void gi_gemm_kernel(
    const float* __restrict__ x, const float* __restrict__ b_ih,
    const float* __restrict__ b_hh, const __bf16* __restrict__ wih,
    const int* __restrict__ tte, __bf16* __restrict__ gi) {
  const int tid = threadIdx.x;
  const int lane = tid & 63, w = tid >> 6;
  const int l15 = lane & 15, lg = lane >> 4, kofs = lg * 8;
  const int bblk = blockIdx.x & 63, tgrp = blockIdx.x >> 6;
  const int b0 = bblk * 16;

  int tmaxB = 0;
  for (int i = 0; i < 16; ++i) tmaxB = max(tmaxB, tte[b0 + i]);
  if (tgrp * 16 > tmaxB) return;

  bf16x8 wf[6][4];
  float bias[6];
#pragma unroll
  for (int tile = 0; tile < 6; ++tile) {
    const int gate = tile >> 1;
    const int c = w * 32 + (tile & 1) * 16 + l15;
    const int col = gate * 256 + c;
#pragma unroll
    for (int kt = 0; kt < 4; ++kt) wf[tile][kt] = ld8(wih + (size_t)col * 128 + kt * 32 + kofs);
    bias[tile] = (gate == 0) ? b_ih[c] + b_hh[c]
               : (gate == 1) ? b_ih[256 + c] + b_hh[256 + c]
                             : b_ih[512 + c];
  }

#pragma unroll 1
  for (int ti = 0; ti < 16; ++ti) {
    const int t = tgrp * 16 + ti;
    if (t > tmaxB) break;
    const float* xb = x + ((size_t)(b0 + l15) * L_ + t) * F_ + kofs;
    bf16x8 xfr[4];
#pragma unroll
    for (int kt = 0; kt < 4; ++kt) {
      float4 a = *(const float4*)(xb + kt * 32);
      float4 b = *(const float4*)(xb + kt * 32 + 4);
      xfr[kt][0] = (__bf16)a.x; xfr[kt][1] = (__bf16)a.y;
      xfr[kt][2] = (__bf16)a.z; xfr[kt][3] = (__bf16)a.w;
      xfr[kt][4] = (__bf16)b.x; xfr[kt][5] = (__bf16)b.y;
      xfr[kt][6] = (__bf16)b.z; xfr[kt][7] = (__bf16)b.w;
    }
    f32x4 acc[6];
#pragma unroll
    for (int tile = 0; tile < 6; ++tile) {
      acc[tile][0] = bias[tile]; acc[tile][1] = bias[tile];
      acc[tile][2] = bias[tile]; acc[tile][3] = bias[tile];
    }
#pragma unroll
    for (int kt = 0; kt < 4; ++kt)
#pragma unroll
      for (int tile = 0; tile < 6; ++tile)
        acc[tile] = MFMA16(xfr[kt], wf[tile][kt], acc[tile]);

    const size_t chunk = (((size_t)t * 64 + bblk) * 8 + w) * 6;
#pragma unroll
    for (int tile = 0; tile < 6; ++tile) {
      bf16x4 pk;
      pk[0] = (__bf16)acc[tile][0]; pk[1] = (__bf16)acc[tile][1];
      pk[2] = (__bf16)acc[tile][2]; pk[3] = (__bf16)acc[tile][3];
      *(bf16x4*)(gi + (chunk + tile) * 256 + (lg * 16 + l15) * 4) = pk;
    }
  }
}

// ---- recurrence gru7: i8 weights. r,z (128 KB i8) LDS-resident (16B-granule
// XOR swizzle); n gate in 8 loop-invariant v4i32 frags/lane. h state in f32
// regs (hprev); h quantized to i8 in hbuf for the next step's A-operand.
// mfma_i32_16x16x64_i8, 24 MFMA/wave/step, 1 barrier/step. 64 blocks. ----
__global__ __launch_bounds__(512) void gru7_kernel(
    const int* __restrict__ tte, const float* __restrict__ b_hh,
    const signed char* __restrict__ wq_rz, const signed char* __restrict__ wqn_f,
    const float* __restrict__ dq, const __bf16* __restrict__ gi,
    __bf16* __restrict__ hid) {
  __shared__ signed char wlds[512 * 256];   // 128 KB
  __shared__ signed char hb[2][16][272];    // 8.5 KB
  const int tid = threadIdx.x;
  const int lane = tid & 63, w = tid >> 6;
  const int l15 = lane & 15, lg = lane >> 4;
  const int b0 = blockIdx.x * 16;

  // stage r,z into LDS: granule g (16B) of row -> phys granule g ^ (row&15)
  for (int idx = tid; idx < 8192; idx += 512) {
    const int row = idx >> 4, g = idx & 15;
    uint4 v = *(const uint4*)(wq_rz + (size_t)row * 256 + g * 16);
    *(uint4*)&wlds[row * 256 + ((g ^ (row & 15)) << 4)] = v;
  }
  for (int i = tid; i < 2 * 16 * 272; i += 512) ((signed char*)hb)[i] = 0;

  int colL[2];
  float dqR[2], dqZ[2], dqN[2], bhn[2];
#pragma unroll
  for (int hf = 0; hf < 2; ++hf) {
    colL[hf] = w * 32 + hf * 16 + l15;
    dqR[hf] = dq[colL[hf]];
    dqZ[hf] = dq[256 + colL[hf]];
    dqN[hf] = dq[512 + colL[hf]];
    bhn[hf] = b_hh[512 + colL[hf]];
  }

  int tteC[4];
#pragma unroll
  for (int r = 0; r < 4; ++r) tteC[r] = tte[b0 + 4 * lg + r];
  int tmax = 0;
  for (int i = 0; i < 16; ++i) tmax = max(tmax, tte[b0 + i]);

  // gi base; per-t stride = 64*8*6*256 = 786432 bf16
  const __bf16* gib = gi + ((size_t)blockIdx.x * 8 + w) * 6 * 256 + (lg * 16 + l15) * 4;
  bf16x4 g[6];
#pragma unroll
  for (int tile = 0; tile < 6; ++tile) g[tile] = *(const bf16x4*)(gib + tile * 256);

  // n-weight fragments (loop-invariant, 8 x 16B = 32 regs)
  i32x4 nw[2][4];
#pragma unroll
  for (int hf = 0; hf < 2; ++hf)
#pragma unroll
    for (int kt = 0; kt < 4; ++kt)
      nw[hf][kt] = *(const i32x4*)(wqn_f + ((((w * 2 + hf) * 4) + kt) * 64 + lane) * 16);

  float hprev[2][4];
#pragma unroll
  for (int hf = 0; hf < 2; ++hf)
#pragma unroll
    for (int r = 0; r < 4; ++r) hprev[hf][r] = 0.f;

  __syncthreads();

#pragma unroll 1
  for (int t = 0; t < tmax; ++t) {
    const int c = t & 1, nc = c ^ 1;
    i32x4 aR[2] = {{0, 0, 0, 0}, {0, 0, 0, 0}};
    i32x4 aZ[2] = {{0, 0, 0, 0}, {0, 0, 0, 0}};
    i32x4 aN[2] = {{0, 0, 0, 0}, {0, 0, 0, 0}};

    bf16x4 gc[6];
#pragma unroll
    for (int tile = 0; tile < 6; ++tile) gc[tile] = g[tile];
    const __bf16* gp = gib + (size_t)min(t + 1, 255) * 786432;
#pragma unroll
    for (int tile = 0; tile < 6; ++tile) g[tile] = *(const bf16x4*)(gp + tile * 256);

    // gh: A = h_q rows (16B/lane), B = swizzled LDS (r,z) + reg frags (n)
#pragma unroll
    for (int kt = 0; kt < 4; ++kt) {
      const i32x4 hA = *(const i32x4*)&hb[c][l15][kt * 64 + lg * 16];
      const int gsw = ((kt * 4 + lg) ^ l15) << 4;
#pragma unroll
      for (int hf = 0; hf < 2; ++hf) {
        const i32x4 bR = *(const i32x4*)&wlds[colL[hf] * 256 + gsw];
        const i32x4 bZ = *(const i32x4*)&wlds[(256 + colL[hf]) * 256 + gsw];
        aR[hf] = MFMA_I8(hA, bR, aR[hf]);
        aZ[hf] = MFMA_I8(hA, bZ, aZ[hf]);
        aN[hf] = MFMA_I8(hA, nw[hf][kt], aN[hf]);
      }
    }

    // gates + state update; write h_q for next step, bf16 h to hid
#pragma unroll
    for (int hf = 0; hf < 2; ++hf)
#pragma unroll
      for (int r = 0; r < 4; ++r) {
        const int row = 4 * lg + r;
        const float rg = sigm((float)gc[0 + hf][r] + (float)aR[hf][r] * dqR[hf]);
        const float zg = sigm((float)gc[2 + hf][r] + (float)aZ[hf][r] * dqZ[hf]);
        const float ng = tanh_f((float)gc[4 + hf][r] + rg * ((float)aN[hf][r] * dqN[hf] + bhn[hf]));
        const float hold = hprev[hf][r];
        const float hnew = zg * (hold - ng) + ng;
        const float hw = (t < tteC[r]) ? hnew : hold;
        hprev[hf][r] = hw;
        hb[nc][row][colL[hf]] = (signed char)__float2int_rn(hw * 127.f);
        if (t < tteC[r])
          hid[((size_t)(b0 + row) * L_ + t) * H_ + colL[hf]] = (__bf16)hw;
      }
    __syncthreads();
  }
}

// ---- out = mask ? hid@W_out^T + b_out : 0  (writes zeros; no d_out memset) ----
__global__ __launch_bounds__(512, 2) void out_gemm_kernel(
    const __bf16* __restrict__ hid, const __bf16* __restrict__ wout,
    const float* __restrict__ b_out, const int* __restrict__ tte,
    float* __restrict__ out) {
  const int tid = threadIdx.x;
  const int lane = tid & 63, w = tid >> 6;
  const int l15 = lane & 15, lg = lane >> 4, kofs = lg * 8;
  const int row0 = blockIdx.x * 128 + w * 16;
  const int bI = row0 >> 8;
  const int tteB = tte[bI];
  const int tbase = row0 & 255;

  f32x4 acc[8];
#pragma unroll
  for (int tile = 0; tile < 8; ++tile) { acc[tile][0] = 0; acc[tile][1] = 0; acc[tile][2] = 0; acc[tile][3] = 0; }
#pragma unroll
  for (int kt = 0; kt < 8; ++kt) {
    const bf16x8 af = *(const bf16x8*)(hid + (size_t)(row0 + l15) * H_ + kt * 32 + kofs);
#pragma unroll
    for (int tile = 0; tile < 8; ++tile)
      acc[tile] = MFMA16(af, ld8(wout + (size_t)(tile * 16 + l15) * H_ + kt * 32 + kofs), acc[tile]);
  }
#pragma unroll
  for (int tile = 0; tile < 8; ++tile) {
    const float bo = b_out[tile * 16 + l15];
#pragma unroll
    for (int r = 0; r < 4; ++r) {
      const int R = row0 + 4 * lg + r;
      const int t = tbase + 4 * lg + r;
      out[(size_t)R * F_ + tile * 16 + l15] = (t < tteB) ? acc[tile][r] + bo : 0.f;
    }
  }
}

// ---- decoder: attention (MFMA scores), softmax, context, MLP, final softmax ----
__global__ __launch_bounds__(256, 2) void decoder_kernel(
    const float* __restrict__ x, const int* __restrict__ tte,
    const __bf16* __restrict__ hid, const __bf16* __restrict__ wa_t,
    const float* __restrict__ va, const float* __restrict__ Ua,
    const float* __restrict__ W1, const float* __restrict__ b1,
    const float* __restrict__ W2, const float* __restrict__ b2,
    float* __restrict__ fht) {
  __shared__ float last_s[128], u_s[128], s_s[256], alpha_s[256], ctx_s[256], z1_s[256], red_s[8];
  const int tid = threadIdx.x;
  const int b = blockIdx.x;
  const int tb = tte[b];
  if (tid < 128) last_s[tid] = x[((size_t)b * L_ + tb) * F_ + tid];
  __syncthreads();
  if (tid < 128) {
    float a = 0.f;
    for (int f = 0; f < 128; ++f) a += last_s[f] * Ua[f * 128 + tid];
    u_s[tid] = a;
  }
  __syncthreads();
  const int lane = tid & 63, w = tid >> 6, l15 = lane & 15, lg = lane >> 4, kofs = lg * 8;
#pragma unroll 1
  for (int mi = 0; mi < 4; ++mi) {
    const int mtile = w * 4 + mi;
    const int trow = mtile * 16 + l15;
    f32x4 sacc[8];
#pragma unroll
    for (int ct = 0; ct < 8; ++ct) { sacc[ct][0] = 0; sacc[ct][1] = 0; sacc[ct][2] = 0; sacc[ct][3] = 0; }
#pragma unroll
    for (int kt = 0; kt < 8; ++kt) {
      bf16x8 af = *(const bf16x8*)&hid[((size_t)b * L_ + trow) * H_ + kt * 32 + kofs];
#pragma unroll
      for (int ct = 0; ct < 8; ++ct) {
        bf16x8 bf = *(const bf16x8*)&wa_t[(size_t)(ct * 16 + l15) * 256 + kt * 32 + kofs];
        sacc[ct] = MFMA16(af, bf, sacc[ct]);
      }
    }
    float sp[4] = {0, 0, 0, 0};
#pragma unroll
    for (int ct = 0; ct < 8; ++ct) {
      int a = ct * 16 + l15;
      float ua = u_s[a], vv = va[a];
#pragma unroll
      for (int r = 0; r < 4; ++r) sp[r] += tanh_f(sacc[ct][r] + ua) * vv;
    }
#pragma unroll
    for (int r = 0; r < 4; ++r) {
      sp[r] += __shfl_xor(sp[r], 1);
      sp[r] += __shfl_xor(sp[r], 2);
      sp[r] += __shfl_xor(sp[r], 4);
      sp[r] += __shfl_xor(sp[r], 8);
    }
    if (l15 == 0) {
#pragma unroll
      for (int r = 0; r < 4; ++r) s_s[mtile * 16 + 4 * lg + r] = sp[r];
    }
  }
  __syncthreads();
  const float sv = s_s[tid];
  float wm = wave_max(sv);
  if (lane == 0) red_s[w] = wm;
  __syncthreads();
  const float m = fmaxf(fmaxf(red_s[0], red_s[1]), fmaxf(red_s[2], red_s[3]));
  const float e = __expf(sv - m);
  alpha_s[tid] = e;
  float wsum = wave_sum(e);
  if (lane == 0) red_s[4 + w] = wsum;
  __syncthreads();
  const float inv = 1.f / (red_s[4] + red_s[5] + red_s[6] + red_s[7]);
  float cacc = 0.f;
  for (int t = 0; t < 256; ++t)
    cacc += alpha_s[t] * (float)hid[((size_t)b * L_ + t) * H_ + tid];
  ctx_s[tid] = cacc * inv;
  __syncthreads();
  float a1 = b1[tid];
  for (int k = 0; k < 256; ++k) a1 += ctx_s[k] * W1[k * 256 + tid];
  for (int k = 0; k < 128; ++k) a1 += last_s[k] * W1[(256 + k) * 256 + tid];
  z1_s[tid] = fmaxf(a1, 0.f);
  __syncthreads();
  float o0 = b2[tid], o1 = b2[tid + 256];
  for (int k = 0; k < 256; ++k) {
    float zv = z1_s[k];
    o0 += zv * W2[k * 512 + tid];
    o1 += zv * W2[k * 512 + tid + 256];
  }
  float wm2 = wave_max(fmaxf(o0, o1));
  if (lane == 0) red_s[w] = wm2;
  __syncthreads();
  const float m2 = fmaxf(fmaxf(red_s[0], red_s[1]), fmaxf(red_s[2], red_s[3]));
  const float e0 = __expf(o0 - m2), e1 = __expf(o1 - m2);
  float ws2 = wave_sum(e0 + e1);
  if (lane == 0) red_s[4 + w] = ws2;
  __syncthreads();
  const float inv2 = 1.f / (red_s[4] + red_s[5] + red_s[6] + red_s[7]);
  fht[(size_t)b * 512 + tid] = e0 * inv2;
  fht[(size_t)b * 512 + tid + 256] = e1 * inv2;
}

extern "C" void kernel_launch(void* const* d_in, const int* in_sizes, int n_in,
                              void* d_out, int out_size, void* d_ws, size_t ws_size,
                              hipStream_t stream) {
  const float* x = (const float*)d_in[0];
  const int* tte = (const int*)d_in[1];
  const float* W_ih = (const float*)d_in[2];
  const float* W_hh = (const float*)d_in[3];
  const float* b_ih = (const float*)d_in[4];
  const float* b_hh = (const float*)d_in[5];
  const float* W_out = (const float*)d_in[6];
  const float* b_out = (const float*)d_in[7];
  const float* Wa = (const float*)d_in[8];
  const float* Ua = (const float*)d_in[9];
  const float* va = (const float*)d_in[10];
  const float* W1 = (const float*)d_in[11];
  const float* b1 = (const float*)d_in[12];
  const float* W2 = (const float*)d_in[13];
  const float* b2 = (const float*)d_in[14];

  char* ws = (char*)d_ws;
  __bf16* wih = (__bf16*)(ws + 0);                 // 196608 B
  __bf16* wout = (__bf16*)(ws + 196608);           // 65536 B
  __bf16* wa_t = (__bf16*)(ws + 262144);           // 65536 B
  signed char* wq_rz = (signed char*)(ws + 327680); // 131072 B
  signed char* wqn_f = (signed char*)(ws + 458752); // 65536 B
  float* dq = (float*)(ws + 524288);               // 3072 B
  __bf16* hid = (__bf16*)(ws + 1048576);           // 134217728 B
  __bf16* gi = (__bf16*)(ws + 135266304);          // 402653184 B

  float* out = (float*)d_out;
  float* fht = out + (size_t)33554432;

  hipMemsetAsync(hid, 0, (size_t)134217728, stream);   // zero hidden past tte
  cvt_kernel<<<640, 256, 0, stream>>>(W_ih, W_out, Wa, wih, wout, wa_t);
  quant_kernel<<<3, 256, 0, stream>>>(W_hh, wq_rz, wqn_f, dq);
  gi_gemm_kernel<<<1024, 512, 0, stream>>>(x, b_ih, b_hh, wih, tte, gi);
  gru7_kernel<<<64, 512, 0, stream>>>(tte, b_hh, wq_rz, wqn_f, dq, gi, hid);
  out_gemm_kernel<<<2048, 512, 0, stream>>>(hid, wout, b_out, tte, out);
  decoder_kernel<<<1024, 256, 0, stream>>>(x, tte, hid, wa_t, va, Ua, W1, b1, W2, b2, fht);
}

// Round 12
// 1095.392 us; speedup vs baseline: 3.4380x; 1.2017x over previous
//
#include <hip/hip_runtime.h>

// B=1024, L=256, F=128, H=256, 3H=768, A=128, CH=256, OUT=512
#define B_ 1024
#define L_ 256
#define F_ 128
#define H_ 256

typedef __bf16 bf16x8 __attribute__((ext_vector_type(8)));
typedef __bf16 bf16x4 __attribute__((ext_vector_type(4)));
typedef float f32x4 __attribute__((ext_vector_type(4)));
typedef int i32x4 __attribute__((ext_vector_type(4)));

#define MFMA16(a, b, c) __builtin_amdgcn_mfma_f32_16x16x32_bf16((a), (b), (c), 0, 0, 0)
#define MFMA_I8(a, b, c) __builtin_amdgcn_mfma_i32_16x16x64_i8((a), (b), (c), 0, 0, 0)
// barrier WITHOUT vmcnt drain: LDS ordering only; VMEM stays in flight
#define BAR_LDS() asm volatile("s_waitcnt lgkmcnt(0)\n\ts_barrier" ::: "memory")

__device__ __forceinline__ float rcp_f(float x) { return __builtin_amdgcn_rcpf(x); }
__device__ __forceinline__ float sigm(float x) { return rcp_f(1.f + __expf(-x)); }
__device__ __forceinline__ float tanh_f(float x) {
  float ax = fabsf(x);
  float e = __expf(-2.f * ax);
  float r = (1.f - e) * rcp_f(1.f + e);
  return copysignf(r, x);
}
__device__ __forceinline__ bf16x8 ld8(const __bf16* p) { return *(const bf16x8*)p; }
__device__ __forceinline__ float wave_max(float v) {
#pragma unroll
  for (int d = 1; d < 64; d <<= 1) v = fmaxf(v, __shfl_xor(v, d));
  return v;
}
__device__ __forceinline__ float wave_sum(float v) {
#pragma unroll
  for (int d = 1; d < 64; d <<= 1) v += __shfl_xor(v, d);
  return v;
}

// ---- weight conversion: f32 -> bf16 (Wa transposed to [A][H]); W_hh handled by quant ----
__global__ void cvt_kernel(const float* __restrict__ wih_f, const float* __restrict__ wout_f,
                           const float* __restrict__ wa_f,
                           __bf16* __restrict__ wih, __bf16* __restrict__ wout,
                           __bf16* __restrict__ wa_t) {
  int i = blockIdx.x * 256 + threadIdx.x;
  if (i < 98304) wih[i] = (__bf16)wih_f[i];                            // [768][128]
  else if (i < 131072) wout[i - 98304] = (__bf16)wout_f[i - 98304];    // [128][256]
  else if (i < 163840) {                                               // Wa[k][a] -> wa_t[a][k]
    int j = i - 131072;
    int a = j >> 8, k = j & 255;
    wa_t[j] = (__bf16)wa_f[k * 128 + a];
  }
}

// ---- quantize W_hh to i8 with per-row scales (unchanged from R11) ----
__global__ void quant_kernel(const float* __restrict__ whh_f,
                             signed char* __restrict__ wq_rz,
                             signed char* __restrict__ wqn_f,
                             float* __restrict__ dq) {
  const int c = blockIdx.x * 256 + threadIdx.x;
  if (c >= 768) return;
  const float* row = whh_f + (size_t)c * 256;
  float m = 0.f;
  for (int k = 0; k < 256; ++k) m = fmaxf(m, fabsf(row[k]));
  const float inv = (m > 1e-30f) ? 127.f / m : 0.f;
  dq[c] = m / 16129.f;
  if (c < 512) {
    for (int k = 0; k < 256; ++k)
      wq_rz[(size_t)c * 256 + k] = (signed char)__float2int_rn(row[k] * inv);
  } else {
    const int cN = c - 512;
    const int w = cN >> 5, hf = (cN >> 4) & 1, l15 = cN & 15;
    for (int k = 0; k < 256; ++k) {
      const int kt = k >> 6, lg = (k >> 4) & 3, j = k & 15;
      const int lane = lg * 16 + l15;
      wqn_f[((((w * 2 + hf) * 4) + kt) * 64 + lane) * 16 + j] =
          (signed char)__float2int_rn(row[k] * inv);
    }
  }
}

// ---- gi precompute (8-wave layout): gi[b,t,:] = x[b,t]@W_ih^T (+ folded biases),
// chunk = ((t*64+bblk)*8+w)*6+tile, tile = gate*2+hf; within: (lg*16+l15)*4+r ----
__global__ __launch_bounds__(512, 2) void gi_gemm_kernel(
    const float* __restrict__ x, const float* __restrict__ b_ih,
    const float* __restrict__ b_hh, const __bf16* __restrict__ wih,
    const int* __restrict__ tte, __bf16* __restrict__ gi) {
  const int tid = threadIdx.x;
  const int lane = tid & 63, w = tid >> 6;
  const int l15 = lane & 15, lg = lane >> 4, kofs = lg * 8;
  const int bblk = blockIdx.x & 63, tgrp = blockIdx.x >> 6;
  const int b0 = bblk * 16;

  int tmaxB = 0;
  for (int i = 0; i < 16; ++i) tmaxB = max(tmaxB, tte[b0 + i]);
  if (tgrp * 16 > tmaxB) return;

  bf16x8 wf[6][4];
  float bias[6];
#pragma unroll
  for (int tile = 0; tile < 6; ++tile) {
    const int gate = tile >> 1;
    const int c = w * 32 + (tile & 1) * 16 + l15;
    const int col = gate * 256 + c;
#pragma unroll
    for (int kt = 0; kt < 4; ++kt) wf[tile][kt] = ld8(wih + (size_t)col * 128 + kt * 32 + kofs);
    bias[tile] = (gate == 0) ? b_ih[c] + b_hh[c]
               : (gate == 1) ? b_ih[256 + c] + b_hh[256 + c]
                             : b_ih[512 + c];
  }

#pragma unroll 1
  for (int ti = 0; ti < 16; ++ti) {
    const int t = tgrp * 16 + ti;
    if (t > tmaxB) break;
    const float* xb = x + ((size_t)(b0 + l15) * L_ + t) * F_ + kofs;
    bf16x8 xfr[4];
#pragma unroll
    for (int kt = 0; kt < 4; ++kt) {
      float4 a = *(const float4*)(xb + kt * 32);
      float4 b = *(const float4*)(xb + kt * 32 + 4);
      xfr[kt][0] = (__bf16)a.x; xfr[kt][1] = (__bf16)a.y;
      xfr[kt][2] = (__bf16)a.z; xfr[kt][3] = (__bf16)a.w;
      xfr[kt][4] = (__bf16)b.x; xfr[kt][5] = (__bf16)b.y;
      xfr[kt][6] = (__bf16)b.z; xfr[kt][7] = (__bf16)b.w;
    }
    f32x4 acc[6];
#pragma unroll
    for (int tile = 0; tile < 6; ++tile) {
      acc[tile][0] = bias[tile]; acc[tile][1] = bias[tile];
      acc[tile][2] = bias[tile]; acc[tile][3] = bias[tile];
    }
#pragma unroll
    for (int kt = 0; kt < 4; ++kt)
#pragma unroll
      for (int tile = 0; tile < 6; ++tile)
        acc[tile] = MFMA16(xfr[kt], wf[tile][kt], acc[tile]);

    const size_t chunk = (((size_t)t * 64 + bblk) * 8 + w) * 6;
#pragma unroll
    for (int tile = 0; tile < 6; ++tile) {
      bf16x4 pk;
      pk[0] = (__bf16)acc[tile][0]; pk[1] = (__bf16)acc[tile][1];
      pk[2] = (__bf16)acc[tile][2]; pk[3] = (__bf16)acc[tile][3];
      *(bf16x4*)(gi + (chunk + tile) * 256 + (lg * 16 + l15) * 4) = pk;
    }
  }
}

// ---- recurrence gru8: gru7 + (a) lgkmcnt-only barrier (no vmcnt drain ->
// gi prefetch/stores stay in flight), (b) rcp-based gates (no div sequences),
// (c) bf16 h mirrored in LDS, ONE coalesced 16B hid store per thread. ----
__global__ __launch_bounds__(512) void gru8_kernel(
    const int* __restrict__ tte, const float* __restrict__ b_hh,
    const signed char* __restrict__ wq_rz, const signed char* __restrict__ wqn_f,
    const float* __restrict__ dq, const __bf16* __restrict__ gi,
    __bf16* __restrict__ hid) {
  __shared__ signed char wlds[512 * 256];   // 128 KB
  __shared__ signed char hb[2][16][272];    // 8.5 KB (i8 h, MFMA A-operand)
  __shared__ __bf16 hbf[2][16][264];        // 16.5 KB (bf16 h, store staging)
  const int tid = threadIdx.x;
  const int lane = tid & 63, w = tid >> 6;
  const int l15 = lane & 15, lg = lane >> 4;
  const int b0 = blockIdx.x * 16;

  // stage r,z into LDS: granule g (16B) of row -> phys granule g ^ (row&15)
  for (int idx = tid; idx < 8192; idx += 512) {
    const int row = idx >> 4, g = idx & 15;
    uint4 v = *(const uint4*)(wq_rz + (size_t)row * 256 + g * 16);
    *(uint4*)&wlds[row * 256 + ((g ^ (row & 15)) << 4)] = v;
  }
  for (int i = tid; i < 2 * 16 * 272; i += 512) ((signed char*)hb)[i] = 0;

  int colL[2];
  float dqR[2], dqZ[2], dqN[2], bhn[2];
#pragma unroll
  for (int hf = 0; hf < 2; ++hf) {
    colL[hf] = w * 32 + hf * 16 + l15;
    dqR[hf] = dq[colL[hf]];
    dqZ[hf] = dq[256 + colL[hf]];
    dqN[hf] = dq[512 + colL[hf]];
    bhn[hf] = b_hh[512 + colL[hf]];
  }

  int tteC[4];
#pragma unroll
  for (int r = 0; r < 4; ++r) tteC[r] = tte[b0 + 4 * lg + r];
  const int rowS = tid >> 5, segS = tid & 31;
  const int tteS = tte[b0 + rowS];
  int tmax = 0;
  for (int i = 0; i < 16; ++i) tmax = max(tmax, tte[b0 + i]);

  // gi base; per-t stride = 64*8*6*256 = 786432 bf16
  const __bf16* gib = gi + ((size_t)blockIdx.x * 8 + w) * 6 * 256 + (lg * 16 + l15) * 4;
  bf16x4 g[6];
#pragma unroll
  for (int tile = 0; tile < 6; ++tile) g[tile] = *(const bf16x4*)(gib + tile * 256);

  // n-weight fragments (loop-invariant, 8 x 16B = 32 regs)
  i32x4 nw[2][4];
#pragma unroll
  for (int hf = 0; hf < 2; ++hf)
#pragma unroll
    for (int kt = 0; kt < 4; ++kt)
      nw[hf][kt] = *(const i32x4*)(wqn_f + ((((w * 2 + hf) * 4) + kt) * 64 + lane) * 16);

  float hprev[2][4];
#pragma unroll
  for (int hf = 0; hf < 2; ++hf)
#pragma unroll
    for (int r = 0; r < 4; ++r) hprev[hf][r] = 0.f;

  __syncthreads();   // init fence (full drain once is fine)

#pragma unroll 1
  for (int t = 0; t < tmax; ++t) {
    const int c = t & 1, nc = c ^ 1;

    // issue next step's gi prefetch FIRST (stays in flight across barriers)
    bf16x4 gc[6];
#pragma unroll
    for (int tile = 0; tile < 6; ++tile) gc[tile] = g[tile];
    const __bf16* gp = gib + (size_t)min(t + 1, 255) * 786432;
#pragma unroll
    for (int tile = 0; tile < 6; ++tile) g[tile] = *(const bf16x4*)(gp + tile * 256);

    i32x4 aR[2] = {{0, 0, 0, 0}, {0, 0, 0, 0}};
    i32x4 aZ[2] = {{0, 0, 0, 0}, {0, 0, 0, 0}};
    i32x4 aN[2] = {{0, 0, 0, 0}, {0, 0, 0, 0}};

    // gh: A = h_q rows (16B/lane), B = swizzled LDS (r,z) + reg frags (n)
#pragma unroll
    for (int kt = 0; kt < 4; ++kt) {
      const i32x4 hA = *(const i32x4*)&hb[c][l15][kt * 64 + lg * 16];
      const int gsw = ((kt * 4 + lg) ^ l15) << 4;
#pragma unroll
      for (int hf = 0; hf < 2; ++hf) {
        const i32x4 bR = *(const i32x4*)&wlds[colL[hf] * 256 + gsw];
        const i32x4 bZ = *(const i32x4*)&wlds[(256 + colL[hf]) * 256 + gsw];
        aR[hf] = MFMA_I8(hA, bR, aR[hf]);
        aZ[hf] = MFMA_I8(hA, bZ, aZ[hf]);
        aN[hf] = MFMA_I8(hA, nw[hf][kt], aN[hf]);
      }
    }

    // gates + state update; h_q + bf16 h to LDS (no scattered global stores)
#pragma unroll
    for (int hf = 0; hf < 2; ++hf)
#pragma unroll
      for (int r = 0; r < 4; ++r) {
        const int row = 4 * lg + r;
        const float rg = sigm((float)gc[0 + hf][r] + (float)aR[hf][r] * dqR[hf]);
        const float zg = sigm((float)gc[2 + hf][r] + (float)aZ[hf][r] * dqZ[hf]);
        const float ng = tanh_f((float)gc[4 + hf][r] + rg * ((float)aN[hf][r] * dqN[hf] + bhn[hf]));
        const float hold = hprev[hf][r];
        const float hnew = zg * (hold - ng) + ng;
        const float hw = (t < tteC[r]) ? hnew : hold;
        hprev[hf][r] = hw;
        hb[nc][row][colL[hf]] = (signed char)__float2int_rn(hw * 127.f);
        hbf[nc][row][colL[hf]] = (__bf16)hw;
      }
    BAR_LDS();   // LDS ordering only; vmcnt floats

    // coalesced hid store: 1 x 16B per thread (32 threads cover a 512B row)
    if (t < tteS) {
      uint4 v = *(const uint4*)&hbf[nc][rowS][segS * 8];
      *(uint4*)(hid + ((size_t)(b0 + rowS) * L_ + t) * H_ + segS * 8) = v;
    }
  }
}

// ---- out = mask ? hid@W_out^T + b_out : 0  (writes zeros; no d_out memset) ----
__global__ __launch_bounds__(512, 2) void out_gemm_kernel(
    const __bf16* __restrict__ hid, const __bf16* __restrict__ wout,
    const float* __restrict__ b_out, const int* __restrict__ tte,
    float* __restrict__ out) {
  const int tid = threadIdx.x;
  const int lane = tid & 63, w = tid >> 6;
  const int l15 = lane & 15, lg = lane >> 4, kofs = lg * 8;
  const int row0 = blockIdx.x * 128 + w * 16;
  const int bI = row0 >> 8;
  const int tteB = tte[bI];
  const int tbase = row0 & 255;

  f32x4 acc[8];
#pragma unroll
  for (int tile = 0; tile < 8; ++tile) { acc[tile][0] = 0; acc[tile][1] = 0; acc[tile][2] = 0; acc[tile][3] = 0; }
#pragma unroll
  for (int kt = 0; kt < 8; ++kt) {
    const bf16x8 af = *(const bf16x8*)(hid + (size_t)(row0 + l15) * H_ + kt * 32 + kofs);
#pragma unroll
    for (int tile = 0; tile < 8; ++tile)
      acc[tile] = MFMA16(af, ld8(wout + (size_t)(tile * 16 + l15) * H_ + kt * 32 + kofs), acc[tile]);
  }
#pragma unroll
  for (int tile = 0; tile < 8; ++tile) {
    const float bo = b_out[tile * 16 + l15];
#pragma unroll
    for (int r = 0; r < 4; ++r) {
      const int R = row0 + 4 * lg + r;
      const int t = tbase + 4 * lg + r;
      out[(size_t)R * F_ + tile * 16 + l15] = (t < tteB) ? acc[tile][r] + bo : 0.f;
    }
  }
}

// ---- decoder: attention (MFMA scores), softmax, context, MLP, final softmax ----
__global__ __launch_bounds__(256, 2) void decoder_kernel(
    const float* __restrict__ x, const int* __restrict__ tte,
    const __bf16* __restrict__ hid, const __bf16* __restrict__ wa_t,
    const float* __restrict__ va, const float* __restrict__ Ua,
    const float* __restrict__ W1, const float* __restrict__ b1,
    const float* __restrict__ W2, const float* __restrict__ b2,
    float* __restrict__ fht) {
  __shared__ float last_s[128], u_s[128], s_s[256], alpha_s[256], ctx_s[256], z1_s[256], red_s[8];
  const int tid = threadIdx.x;
  const int b = blockIdx.x;
  const int tb = tte[b];
  if (tid < 128) last_s[tid] = x[((size_t)b * L_ + tb) * F_ + tid];
  __syncthreads();
  if (tid < 128) {
    float a = 0.f;
    for (int f = 0; f < 128; ++f) a += last_s[f] * Ua[f * 128 + tid];
    u_s[tid] = a;
  }
  __syncthreads();
  const int lane = tid & 63, w = tid >> 6, l15 = lane & 15, lg = lane >> 4, kofs = lg * 8;
#pragma unroll 1
  for (int mi = 0; mi < 4; ++mi) {
    const int mtile = w * 4 + mi;
    const int trow = mtile * 16 + l15;
    f32x4 sacc[8];
#pragma unroll
    for (int ct = 0; ct < 8; ++ct) { sacc[ct][0] = 0; sacc[ct][1] = 0; sacc[ct][2] = 0; sacc[ct][3] = 0; }
#pragma unroll
    for (int kt = 0; kt < 8; ++kt) {
      bf16x8 af = *(const bf16x8*)&hid[((size_t)b * L_ + trow) * H_ + kt * 32 + kofs];
#pragma unroll
      for (int ct = 0; ct < 8; ++ct) {
        bf16x8 bf = *(const bf16x8*)&wa_t[(size_t)(ct * 16 + l15) * 256 + kt * 32 + kofs];
        sacc[ct] = MFMA16(af, bf, sacc[ct]);
      }
    }
    float sp[4] = {0, 0, 0, 0};
#pragma unroll
    for (int ct = 0; ct < 8; ++ct) {
      int a = ct * 16 + l15;
      float ua = u_s[a], vv = va[a];
#pragma unroll
      for (int r = 0; r < 4; ++r) sp[r] += tanh_f(sacc[ct][r] + ua) * vv;
    }
#pragma unroll
    for (int r = 0; r < 4; ++r) {
      sp[r] += __shfl_xor(sp[r], 1);
      sp[r] += __shfl_xor(sp[r], 2);
      sp[r] += __shfl_xor(sp[r], 4);
      sp[r] += __shfl_xor(sp[r], 8);
    }
    if (l15 == 0) {
#pragma unroll
      for (int r = 0; r < 4; ++r) s_s[mtile * 16 + 4 * lg + r] = sp[r];
    }
  }
  __syncthreads();
  const float sv = s_s[tid];
  float wm = wave_max(sv);
  if (lane == 0) red_s[w] = wm;
  __syncthreads();
  const float m = fmaxf(fmaxf(red_s[0], red_s[1]), fmaxf(red_s[2], red_s[3]));
  const float e = __expf(sv - m);
  alpha_s[tid] = e;
  float wsum = wave_sum(e);
  if (lane == 0) red_s[4 + w] = wsum;
  __syncthreads();
  const float inv = 1.f / (red_s[4] + red_s[5] + red_s[6] + red_s[7]);
  float cacc = 0.f;
  for (int t = 0; t < 256; ++t)
    cacc += alpha_s[t] * (float)hid[((size_t)b * L_ + t) * H_ + tid];
  ctx_s[tid] = cacc * inv;
  __syncthreads();
  float a1 = b1[tid];
  for (int k = 0; k < 256; ++k) a1 += ctx_s[k] * W1[k * 256 + tid];
  for (int k = 0; k < 128; ++k) a1 += last_s[k] * W1[(256 + k) * 256 + tid];
  z1_s[tid] = fmaxf(a1, 0.f);
  __syncthreads();
  float o0 = b2[tid], o1 = b2[tid + 256];
  for (int k = 0; k < 256; ++k) {
    float zv = z1_s[k];
    o0 += zv * W2[k * 512 + tid];
    o1 += zv * W2[k * 512 + tid + 256];
  }
  float wm2 = wave_max(fmaxf(o0, o1));
  if (lane == 0) red_s[w] = wm2;
  __syncthreads();
  const float m2 = fmaxf(fmaxf(red_s[0], red_s[1]), fmaxf(red_s[2], red_s[3]));
  const float e0 = __expf(o0 - m2), e1 = __expf(o1 - m2);
  float ws2 = wave_sum(e0 + e1);
  if (lane == 0) red_s[4 + w] = ws2;
  __syncthreads();
  const float inv2 = 1.f / (red_s[4] + red_s[5] + red_s[6] + red_s[7]);
  fht[(size_t)b * 512 + tid] = e0 * inv2;
  fht[(size_t)b * 512 + tid + 256] = e1 * inv2;
}

extern "C" void kernel_launch(void* const* d_in, const int* in_sizes, int n_in,
                              void* d_out, int out_size, void* d_ws, size_t ws_size,
                              hipStream_t stream) {
  const float* x = (const float*)d_in[0];
  const int* tte = (const int*)d_in[1];
  const float* W_ih = (const float*)d_in[2];
  const float* W_hh = (const float*)d_in[3];
  const float* b_ih = (const float*)d_in[4];
  const float* b_hh = (const float*)d_in[5];
  const float* W_out = (const float*)d_in[6];
  const float* b_out = (const float*)d_in[7];
  const float* Wa = (const float*)d_in[8];
  const float* Ua = (const float*)d_in[9];
  const float* va = (const float*)d_in[10];
  const float* W1 = (const float*)d_in[11];
  const float* b1 = (const float*)d_in[12];
  const float* W2 = (const float*)d_in[13];
  const float* b2 = (const float*)d_in[14];

  char* ws = (char*)d_ws;
  __bf16* wih = (__bf16*)(ws + 0);                 // 196608 B
  __bf16* wout = (__bf16*)(ws + 196608);           // 65536 B
  __bf16* wa_t = (__bf16*)(ws + 262144);           // 65536 B
  signed char* wq_rz = (signed char*)(ws + 327680); // 131072 B
  signed char* wqn_f = (signed char*)(ws + 458752); // 65536 B
  float* dq = (float*)(ws + 524288);               // 3072 B
  __bf16* hid = (__bf16*)(ws + 1048576);           // 134217728 B
  __bf16* gi = (__bf16*)(ws + 135266304);          // 402653184 B

  float* out = (float*)d_out;
  float* fht = out + (size_t)33554432;

  hipMemsetAsync(hid, 0, (size_t)134217728, stream);   // zero hidden past tte
  cvt_kernel<<<640, 256, 0, stream>>>(W_ih, W_out, Wa, wih, wout, wa_t);
  quant_kernel<<<3, 256, 0, stream>>>(W_hh, wq_rz, wqn_f, dq);
  gi_gemm_kernel<<<1024, 512, 0, stream>>>(x, b_ih, b_hh, wih, tte, gi);
  gru8_kernel<<<64, 512, 0, stream>>>(tte, b_hh, wq_rz, wqn_f, dq, gi, hid);
  out_gemm_kernel<<<2048, 512, 0, stream>>>(hid, wout, b_out, tte, out);
  decoder_kernel<<<1024, 256, 0, stream>>>(x, tte, hid, wa_t, va, Ua, W1, b1, W2, b2, fht);
}

// Round 13
// 1025.836 us; speedup vs baseline: 3.6711x; 1.0678x over previous
//
#include <hip/hip_runtime.h>

// B=1024, L=256, F=128, H=256, 3H=768, A=128, CH=256, OUT=512
#define B_ 1024
#define L_ 256
#define F_ 128
#define H_ 256

typedef __bf16 bf16x8 __attribute__((ext_vector_type(8)));
typedef __bf16 bf16x4 __attribute__((ext_vector_type(4)));
typedef float f32x4 __attribute__((ext_vector_type(4)));
typedef int i32x4 __attribute__((ext_vector_type(4)));

#define MFMA16(a, b, c) __builtin_amdgcn_mfma_f32_16x16x32_bf16((a), (b), (c), 0, 0, 0)
#define MFMA_I8(a, b, c) __builtin_amdgcn_mfma_i32_16x16x64_i8((a), (b), (c), 0, 0, 0)
// barrier WITHOUT vmcnt drain: LDS ordering only; VMEM stays in flight
#define BAR_LDS() asm volatile("s_waitcnt lgkmcnt(0)\n\ts_barrier" ::: "memory")

__device__ __forceinline__ float rcp_f(float x) { return __builtin_amdgcn_rcpf(x); }
__device__ __forceinline__ float sigm(float x) { return rcp_f(1.f + __expf(-x)); }
__device__ __forceinline__ float tanh_f(float x) {
  float ax = fabsf(x);
  float e = __expf(-2.f * ax);
  float r = (1.f - e) * rcp_f(1.f + e);
  return copysignf(r, x);
}
__device__ __forceinline__ bf16x8 ld8(const __bf16* p) { return *(const bf16x8*)p; }
__device__ __forceinline__ float wave_max(float v) {
#pragma unroll
  for (int d = 1; d < 64; d <<= 1) v = fmaxf(v, __shfl_xor(v, d));
  return v;
}
__device__ __forceinline__ float wave_sum(float v) {
#pragma unroll
  for (int d = 1; d < 64; d <<= 1) v += __shfl_xor(v, d);
  return v;
}

// ---- weight conversion: f32 -> bf16 (Wa transposed to [A][H]); W_hh handled by quant ----
__global__ void cvt_kernel(const float* __restrict__ wih_f, const float* __restrict__ wout_f,
                           const float* __restrict__ wa_f,
                           __bf16* __restrict__ wih, __bf16* __restrict__ wout,
                           __bf16* __restrict__ wa_t) {
  int i = blockIdx.x * 256 + threadIdx.x;
  if (i < 98304) wih[i] = (__bf16)wih_f[i];                            // [768][128]
  else if (i < 131072) wout[i - 98304] = (__bf16)wout_f[i - 98304];    // [128][256]
  else if (i < 163840) {                                               // Wa[k][a] -> wa_t[a][k]
    int j = i - 131072;
    int a = j >> 8, k = j & 255;
    wa_t[j] = (__bf16)wa_f[k * 128 + a];
  }
}

// ---- quantize W_hh to i8 with per-row scales (unchanged from R11/R12) ----
__global__ void quant_kernel(const float* __restrict__ whh_f,
                             signed char* __restrict__ wq_rz,
                             signed char* __restrict__ wqn_f,
                             float* __restrict__ dq) {
  const int c = blockIdx.x * 256 + threadIdx.x;
  if (c >= 768) return;
  const float* row = whh_f + (size_t)c * 256;
  float m = 0.f;
  for (int k = 0; k < 256; ++k) m = fmaxf(m, fabsf(row[k]));
  const float inv = (m > 1e-30f) ? 127.f / m : 0.f;
  dq[c] = m / 16129.f;
  if (c < 512) {
    for (int k = 0; k < 256; ++k)
      wq_rz[(size_t)c * 256 + k] = (signed char)__float2int_rn(row[k] * inv);
  } else {
    const int cN = c - 512;
    const int w = cN >> 5, hf = (cN >> 4) & 1, l15 = cN & 15;
    for (int k = 0; k < 256; ++k) {
      const int kt = k >> 6, lg = (k >> 4) & 3, j = k & 15;
      const int lane = lg * 16 + l15;
      wqn_f[((((w * 2 + hf) * 4) + kt) * 64 + lane) * 16 + j] =
          (signed char)__float2int_rn(row[k] * inv);
    }
  }
}

// ---- gi precompute (8-wave producer layout, unchanged):
// chunk = ((t*64+bblk)*8+w)*6+tile, tile = gate*2+hf; within: (lg*16+l15)*4+r ----
__global__ __launch_bounds__(512, 2) void gi_gemm_kernel(
    const float* __restrict__ x, const float* __restrict__ b_ih,
    const float* __restrict__ b_hh, const __bf16* __restrict__ wih,
    const int* __restrict__ tte, __bf16* __restrict__ gi) {
  const int tid = threadIdx.x;
  const int lane = tid & 63, w = tid >> 6;
  const int l15 = lane & 15, lg = lane >> 4, kofs = lg * 8;
  const int bblk = blockIdx.x & 63, tgrp = blockIdx.x >> 6;
  const int b0 = bblk * 16;

  int tmaxB = 0;
  for (int i = 0; i < 16; ++i) tmaxB = max(tmaxB, tte[b0 + i]);
  if (tgrp * 16 > tmaxB) return;

  bf16x8 wf[6][4];
  float bias[6];
#pragma unroll
  for (int tile = 0; tile < 6; ++tile) {
    const int gate = tile >> 1;
    const int c = w * 32 + (tile & 1) * 16 + l15;
    const int col = gate * 256 + c;
#pragma unroll
    for (int kt = 0; kt < 4; ++kt) wf[tile][kt] = ld8(wih + (size_t)col * 128 + kt * 32 + kofs);
    bias[tile] = (gate == 0) ? b_ih[c] + b_hh[c]
               : (gate == 1) ? b_ih[256 + c] + b_hh[256 + c]
                             : b_ih[512 + c];
  }

#pragma unroll 1
  for (int ti = 0; ti < 16; ++ti) {
    const int t = tgrp * 16 + ti;
    if (t > tmaxB) break;
    const float* xb = x + ((size_t)(b0 + l15) * L_ + t) * F_ + kofs;
    bf16x8 xfr[4];
#pragma unroll
    for (int kt = 0; kt < 4; ++kt) {
      float4 a = *(const float4*)(xb + kt * 32);
      float4 b = *(const float4*)(xb + kt * 32 + 4);
      xfr[kt][0] = (__bf16)a.x; xfr[kt][1] = (__bf16)a.y;
      xfr[kt][2] = (__bf16)a.z; xfr[kt][3] = (__bf16)a.w;
      xfr[kt][4] = (__bf16)b.x; xfr[kt][5] = (__bf16)b.y;
      xfr[kt][6] = (__bf16)b.z; xfr[kt][7] = (__bf16)b.w;
    }
    f32x4 acc[6];
#pragma unroll
    for (int tile = 0; tile < 6; ++tile) {
      acc[tile][0] = bias[tile]; acc[tile][1] = bias[tile];
      acc[tile][2] = bias[tile]; acc[tile][3] = bias[tile];
    }
#pragma unroll
    for (int kt = 0; kt < 4; ++kt)
#pragma unroll
      for (int tile = 0; tile < 6; ++tile)
        acc[tile] = MFMA16(xfr[kt], wf[tile][kt], acc[tile]);

    const size_t chunk = (((size_t)t * 64 + bblk) * 8 + w) * 6;
#pragma unroll
    for (int tile = 0; tile < 6; ++tile) {
      bf16x4 pk;
      pk[0] = (__bf16)acc[tile][0]; pk[1] = (__bf16)acc[tile][1];
      pk[2] = (__bf16)acc[tile][2]; pk[3] = (__bf16)acc[tile][3];
      *(bf16x4*)(gi + (chunk + tile) * 256 + (lg * 16 + l15) * 4) = pk;
    }
  }
}

// ---- recurrence gru9: 16 waves (1024 thr), 4 waves/SIMD. Wave w owns 16
// H-cols. FUSED out-projection: after the barrier, waves 0-7 compute out-tile
// w from the bf16 h mirror (W_out frags register-resident), waves 8-15 do the
// coalesced hid store. Same i8 W_hh scheme + no-vmcnt-drain barrier as gru8. ----
__global__ __launch_bounds__(1024) void gru9_kernel(
    const int* __restrict__ tte, const float* __restrict__ b_hh,
    const signed char* __restrict__ wq_rz, const signed char* __restrict__ wqn_f,
    const float* __restrict__ dq, const __bf16* __restrict__ gi,
    const __bf16* __restrict__ wout, const float* __restrict__ b_out,
    __bf16* __restrict__ hid, float* __restrict__ out) {
  __shared__ signed char wlds[512 * 256];   // 128 KB
  __shared__ signed char hb[2][16][272];    // 8.5 KB (i8 h, MFMA A-operand)
  __shared__ __bf16 hbf[2][16][260];        // 16.3 KB (bf16 h: out A-op + store)
  const int tid = threadIdx.x;
  const int lane = tid & 63, w = tid >> 6;          // 16 waves
  const int l15 = lane & 15, lg = lane >> 4, kofs = lg * 8;
  const int b0 = blockIdx.x * 16;

  // stage r,z into LDS: granule g (16B) of row -> phys granule g ^ (row&15)
  for (int idx = tid; idx < 8192; idx += 1024) {
    const int row = idx >> 4, g = idx & 15;
    uint4 v = *(const uint4*)(wq_rz + (size_t)row * 256 + g * 16);
    *(uint4*)&wlds[row * 256 + ((g ^ (row & 15)) << 4)] = v;
  }
  for (int i = tid; i < 2 * 16 * 272; i += 1024) ((signed char*)hb)[i] = 0;

  const int colL = w * 16 + l15;            // H-col in [0,256)
  const float dqR = dq[colL], dqZ = dq[256 + colL], dqN = dq[512 + colL];
  const float bhn = b_hh[512 + colL];

  int tteC[4];
#pragma unroll
  for (int r = 0; r < 4; ++r) tteC[r] = tte[b0 + 4 * lg + r];
  const int rowS = (tid >> 5) & 15, segS = tid & 31;   // store mapping (waves 8-15)
  const int tteS = tte[b0 + rowS];
  int tmax = 0;
  for (int i = 0; i < 16; ++i) tmax = max(tmax, tte[b0 + i]);

  // gi base: producer tile = gate*2+hf with 8-wave layout; consumer wave w ->
  // (old wave = w>>1, hf = w&1); gate stride = 2*256 elems
  const __bf16* gib = gi + (((size_t)blockIdx.x * 8 + (w >> 1)) * 6 + (w & 1)) * 256
                    + (lg * 16 + l15) * 4;
  bf16x4 g0 = *(const bf16x4*)(gib);
  bf16x4 g1 = *(const bf16x4*)(gib + 512);
  bf16x4 g2 = *(const bf16x4*)(gib + 1024);

  // n-gate W_hh frags (loop-invariant, 16 regs); layout key = old (w>>1,w&1) pair = w
  i32x4 nw[4];
#pragma unroll
  for (int kt = 0; kt < 4; ++kt)
    nw[kt] = *(const i32x4*)(wqn_f + (size_t)((w * 4 + kt) * 64 + lane) * 16);

  // W_out frags for fused out-projection (tile = w&7; 32 regs, resident)
  const int ocol = (w & 7) * 16 + l15;
  bf16x8 wof[8];
#pragma unroll
  for (int kt = 0; kt < 8; ++kt)
    wof[kt] = ld8(wout + (size_t)ocol * 256 + kt * 32 + kofs);
  const float bo = b_out[ocol];

  float hprev[4] = {0.f, 0.f, 0.f, 0.f};

  __syncthreads();   // init fence (full drain once)

#pragma unroll 1
  for (int t = 0; t < tmax; ++t) {
    const int c = t & 1, nc = c ^ 1;

    // copy current gi, issue next step's prefetch (floats across barriers)
    const bf16x4 gr = g0, gz = g1, gn = g2;
    const __bf16* gp = gib + (size_t)min(t + 1, 255) * 786432;
    g0 = *(const bf16x4*)(gp);
    g1 = *(const bf16x4*)(gp + 512);
    g2 = *(const bf16x4*)(gp + 1024);

    i32x4 aR = {0, 0, 0, 0}, aZ = {0, 0, 0, 0}, aN = {0, 0, 0, 0};
#pragma unroll
    for (int kt = 0; kt < 4; ++kt) {
      const i32x4 hA = *(const i32x4*)&hb[c][l15][kt * 64 + lg * 16];
      const int gsw = ((kt * 4 + lg) ^ l15) << 4;
      aR = MFMA_I8(hA, *(const i32x4*)&wlds[colL * 256 + gsw], aR);
      aZ = MFMA_I8(hA, *(const i32x4*)&wlds[(256 + colL) * 256 + gsw], aZ);
      aN = MFMA_I8(hA, nw[kt], aN);
    }

    // gates + state update; h_q + bf16 h to LDS
#pragma unroll
    for (int r = 0; r < 4; ++r) {
      const int row = 4 * lg + r;
      const float rg = sigm((float)gr[r] + (float)aR[r] * dqR);
      const float zg = sigm((float)gz[r] + (float)aZ[r] * dqZ);
      const float ng = tanh_f((float)gn[r] + rg * ((float)aN[r] * dqN + bhn));
      const float hold = hprev[r];
      const float hnew = zg * (hold - ng) + ng;
      const float hw = (t < tteC[r]) ? hnew : hold;
      hprev[r] = hw;
      hb[nc][row][colL] = (signed char)__float2int_rn(hw * 127.f);
      hbf[nc][row][colL] = (__bf16)hw;
    }
    BAR_LDS();   // LDS ordering only; vmcnt floats

    if (w < 8) {
      // fused out-projection: out[b,t,ocol] = h(t+1) @ W_out^T + b_out (active only)
      f32x4 acc = {0, 0, 0, 0};
#pragma unroll
      for (int kt = 0; kt < 8; ++kt) {
        const bf16x8 af = *(const bf16x8*)&hbf[nc][l15][kt * 32 + kofs];
        acc = MFMA16(af, wof[kt], acc);
      }
#pragma unroll
      for (int r = 0; r < 4; ++r)
        if (t < tteC[r])
          out[((size_t)(b0 + 4 * lg + r) * L_ + t) * F_ + ocol] = acc[r] + bo;
    } else {
      // coalesced hid store: 512 threads x 16B cover 16 rows x 512B
      if (t < tteS) {
        uint4 v = *(const uint4*)&hbf[nc][rowS][segS * 8];
        *(uint4*)(hid + ((size_t)(b0 + rowS) * L_ + t) * H_ + segS * 8) = v;
      }
    }
  }
}

// ---- decoder: attention (MFMA scores), softmax, context, MLP, final softmax ----
__global__ __launch_bounds__(256, 2) void decoder_kernel(
    const float* __restrict__ x, const int* __restrict__ tte,
    const __bf16* __restrict__ hid, const __bf16* __restrict__ wa_t,
    const float* __restrict__ va, const float* __restrict__ Ua,
    const float* __restrict__ W1, const float* __restrict__ b1,
    const float* __restrict__ W2, const float* __restrict__ b2,
    float* __restrict__ fht) {
  __shared__ float last_s[128], u_s[128], s_s[256], alpha_s[256], ctx_s[256], z1_s[256], red_s[8];
  const int tid = threadIdx.x;
  const int b = blockIdx.x;
  const int tb = tte[b];
  if (tid < 128) last_s[tid] = x[((size_t)b * L_ + tb) * F_ + tid];
  __syncthreads();
  if (tid < 128) {
    float a = 0.f;
    for (int f = 0; f < 128; ++f) a += last_s[f] * Ua[f * 128 + tid];
    u_s[tid] = a;
  }
  __syncthreads();
  const int lane = tid & 63, w = tid >> 6, l15 = lane & 15, lg = lane >> 4, kofs = lg * 8;
#pragma unroll 1
  for (int mi = 0; mi < 4; ++mi) {
    const int mtile = w * 4 + mi;
    const int trow = mtile * 16 + l15;
    f32x4 sacc[8];
#pragma unroll
    for (int ct = 0; ct < 8; ++ct) { sacc[ct][0] = 0; sacc[ct][1] = 0; sacc[ct][2] = 0; sacc[ct][3] = 0; }
#pragma unroll
    for (int kt = 0; kt < 8; ++kt) {
      bf16x8 af = *(const bf16x8*)&hid[((size_t)b * L_ + trow) * H_ + kt * 32 + kofs];
#pragma unroll
      for (int ct = 0; ct < 8; ++ct) {
        bf16x8 bf = *(const bf16x8*)&wa_t[(size_t)(ct * 16 + l15) * 256 + kt * 32 + kofs];
        sacc[ct] = MFMA16(af, bf, sacc[ct]);
      }
    }
    float sp[4] = {0, 0, 0, 0};
#pragma unroll
    for (int ct = 0; ct < 8; ++ct) {
      int a = ct * 16 + l15;
      float ua = u_s[a], vv = va[a];
#pragma unroll
      for (int r = 0; r < 4; ++r) sp[r] += tanh_f(sacc[ct][r] + ua) * vv;
    }
#pragma unroll
    for (int r = 0; r < 4; ++r) {
      sp[r] += __shfl_xor(sp[r], 1);
      sp[r] += __shfl_xor(sp[r], 2);
      sp[r] += __shfl_xor(sp[r], 4);
      sp[r] += __shfl_xor(sp[r], 8);
    }
    if (l15 == 0) {
#pragma unroll
      for (int r = 0; r < 4; ++r) s_s[mtile * 16 + 4 * lg + r] = sp[r];
    }
  }
  __syncthreads();
  const float sv = s_s[tid];
  float wm = wave_max(sv);
  if (lane == 0) red_s[w] = wm;
  __syncthreads();
  const float m = fmaxf(fmaxf(red_s[0], red_s[1]), fmaxf(red_s[2], red_s[3]));
  const float e = __expf(sv - m);
  alpha_s[tid] = e;
  float wsum = wave_sum(e);
  if (lane == 0) red_s[4 + w] = wsum;
  __syncthreads();
  const float inv = 1.f / (red_s[4] + red_s[5] + red_s[6] + red_s[7]);
  float cacc = 0.f;
  for (int t = 0; t < 256; ++t)
    cacc += alpha_s[t] * (float)hid[((size_t)b * L_ + t) * H_ + tid];
  ctx_s[tid] = cacc * inv;
  __syncthreads();
  float a1 = b1[tid];
  for (int k = 0; k < 256; ++k) a1 += ctx_s[k] * W1[k * 256 + tid];
  for (int k = 0; k < 128; ++k) a1 += last_s[k] * W1[(256 + k) * 256 + tid];
  z1_s[tid] = fmaxf(a1, 0.f);
  __syncthreads();
  float o0 = b2[tid], o1 = b2[tid + 256];
  for (int k = 0; k < 256; ++k) {
    float zv = z1_s[k];
    o0 += zv * W2[k * 512 + tid];
    o1 += zv * W2[k * 512 + tid + 256];
  }
  float wm2 = wave_max(fmaxf(o0, o1));
  if (lane == 0) red_s[w] = wm2;
  __syncthreads();
  const float m2 = fmaxf(fmaxf(red_s[0], red_s[1]), fmaxf(red_s[2], red_s[3]));
  const float e0 = __expf(o0 - m2), e1 = __expf(o1 - m2);
  float ws2 = wave_sum(e0 + e1);
  if (lane == 0) red_s[4 + w] = ws2;
  __syncthreads();
  const float inv2 = 1.f / (red_s[4] + red_s[5] + red_s[6] + red_s[7]);
  fht[(size_t)b * 512 + tid] = e0 * inv2;
  fht[(size_t)b * 512 + tid + 256] = e1 * inv2;
}

extern "C" void kernel_launch(void* const* d_in, const int* in_sizes, int n_in,
                              void* d_out, int out_size, void* d_ws, size_t ws_size,
                              hipStream_t stream) {
  const float* x = (const float*)d_in[0];
  const int* tte = (const int*)d_in[1];
  const float* W_ih = (const float*)d_in[2];
  const float* W_hh = (const float*)d_in[3];
  const float* b_ih = (const float*)d_in[4];
  const float* b_hh = (const float*)d_in[5];
  const float* W_out = (const float*)d_in[6];
  const float* b_out = (const float*)d_in[7];
  const float* Wa = (const float*)d_in[8];
  const float* Ua = (const float*)d_in[9];
  const float* va = (const float*)d_in[10];
  const float* W1 = (const float*)d_in[11];
  const float* b1 = (const float*)d_in[12];
  const float* W2 = (const float*)d_in[13];
  const float* b2 = (const float*)d_in[14];

  char* ws = (char*)d_ws;
  __bf16* wih = (__bf16*)(ws + 0);                 // 196608 B
  __bf16* wout = (__bf16*)(ws + 196608);           // 65536 B
  __bf16* wa_t = (__bf16*)(ws + 262144);           // 65536 B
  signed char* wq_rz = (signed char*)(ws + 327680); // 131072 B
  signed char* wqn_f = (signed char*)(ws + 458752); // 65536 B
  float* dq = (float*)(ws + 524288);               // 3072 B
  __bf16* hid = (__bf16*)(ws + 1048576);           // 134217728 B
  __bf16* gi = (__bf16*)(ws + 135266304);          // 402653184 B

  float* out = (float*)d_out;
  float* fht = out + (size_t)33554432;

  hipMemsetAsync(d_out, 0, (size_t)out_size * 4, stream);  // zero-padded out (fused writes are masked)
  hipMemsetAsync(hid, 0, (size_t)134217728, stream);       // zero hidden past tte
  cvt_kernel<<<640, 256, 0, stream>>>(W_ih, W_out, Wa, wih, wout, wa_t);
  quant_kernel<<<3, 256, 0, stream>>>(W_hh, wq_rz, wqn_f, dq);
  gi_gemm_kernel<<<1024, 512, 0, stream>>>(x, b_ih, b_hh, wih, tte, gi);
  gru9_kernel<<<64, 1024, 0, stream>>>(tte, b_hh, wq_rz, wqn_f, dq, gi, wout, b_out, hid, out);
  decoder_kernel<<<1024, 256, 0, stream>>>(x, tte, hid, wa_t, va, Ua, W1, b1, W2, b2, fht);
}